// Round 1
// baseline (442.680 us; speedup 1.0000x reference)
//
#include <hip/hip_runtime.h>

typedef unsigned short u16;
typedef unsigned int   u32;

typedef short bf16x8 __attribute__((ext_vector_type(8)));
typedef float f32x4  __attribute__((ext_vector_type(4)));

__device__ __forceinline__ float bf2f(u16 u) { return __uint_as_float(((u32)u) << 16); }
__device__ __forceinline__ u16 f2bf(float f) {
    u32 u = __float_as_uint(f);
    return (u16)((u + 0x7fffu + ((u >> 16) & 1u)) >> 16);
}

#define MFMA16(a, b, c) __builtin_amdgcn_mfma_f32_16x16x32_bf16(a, b, c, 0, 0, 0)

// ---------------------------------------------------------------------------
// K0: transpose x[b][ci][p] fp32 -> xT[b][p][ci] bf16.
// ---------------------------------------------------------------------------
__global__ __launch_bounds__(256, 4) void k_xpose(const float* __restrict__ x,
                                                  u16* __restrict__ xT) {
    __shared__ u16 Xs[128 * 128];
    const int ptile = blockIdx.x, b = blockIdx.y;
    const int t = threadIdx.x;
    const float* xb = x + (((size_t)b) << 21) + ptile * 128;
#pragma unroll
    for (int i = 0; i < 16; ++i) {
        int idx = i * 256 + t;
        int ci = idx >> 5, pq = idx & 31;
        float4 v = *(const float4*)(xb + (((size_t)ci) << 14) + pq * 4);
        u32 lo = (u32)f2bf(v.x) | ((u32)f2bf(v.y) << 16);
        u32 hi = (u32)f2bf(v.z) | ((u32)f2bf(v.w) << 16);
        uint2 pk; pk.x = lo; pk.y = hi;
        int cq = ci >> 3;
        *(uint2*)(&Xs[ci * 128 + ((pq ^ cq) << 2)]) = pk;
    }
    __syncthreads();
    u16* ob = xT + (((size_t)b) << 21) + ((size_t)(ptile * 128)) * 128;
#pragma unroll
    for (int j = 0; j < 8; ++j) {
        int p = j * 16 + (t >> 4), cq = t & 15;
        u16 tmp[8];
#pragma unroll
        for (int c = 0; c < 8; ++c) {
            int ci = cq * 8 + c;
            tmp[c] = Xs[ci * 128 + (((p >> 2) ^ cq) << 2) + (p & 3)];
        }
        *(uint4*)(&ob[(size_t)p * 128 + cq * 8]) = *(const uint4*)tmp;
    }
}

// ---------------------------------------------------------------------------
// K1 v3: qkv 1x1 conv from xT (block = (h, cg, b)), Cs staged in two
// co-halves -> LDS 49 KB -> 3 blocks/CU.
// ---------------------------------------------------------------------------
__global__ __launch_bounds__(512, 6) void k_qkv(const u16* __restrict__ xT,
                                                const float* __restrict__ w,
                                                const float* __restrict__ bias,
                                                u16* __restrict__ out1) {
    extern __shared__ char smem[];
    u16* Bt = (u16*)smem;            // 32 KB swizzled [p][g]
    u16* Cs = Bt + 2048 * 8;         // [64 co][136 p] = 17 KB
    const int h = blockIdx.x, cg = blockIdx.y, b = blockIdx.z;
    const int t = threadIdx.x;

    const u16* xb = xT + (((size_t)b) << 21) + ((size_t)(h * 128)) * 128;
#pragma unroll
    for (int i = 0; i < 4; ++i) {
        int slot = i * 512 + t;
        int p = slot >> 4, g = slot & 15;
        int gg = g ^ (p & 15);
        uint4 v = *(const uint4*)(&xb[p * 128 + gg * 8]);
        *(uint4*)(&Bt[slot * 8]) = v;
    }

    const int wave = t >> 6, lane = t & 63, m16 = lane & 15, quad = lane >> 4;
    bf16x8 afr[4];
    {
        const float* wp0 = w + (size_t)(cg * 128 + wave * 16 + m16) * 128 + quad * 8;
#pragma unroll
        for (int kk = 0; kk < 4; ++kk) {
            float4 w0 = *(const float4*)(wp0 + kk * 32);
            float4 w1 = *(const float4*)(wp0 + kk * 32 + 4);
            bf16x8 a;
            a[0] = (short)f2bf(w0.x); a[1] = (short)f2bf(w0.y);
            a[2] = (short)f2bf(w0.z); a[3] = (short)f2bf(w0.w);
            a[4] = (short)f2bf(w1.x); a[5] = (short)f2bf(w1.y);
            a[6] = (short)f2bf(w1.z); a[7] = (short)f2bf(w1.w);
            afr[kk] = a;
        }
    }
    __syncthreads();

    f32x4 acc[8] = {};
#pragma unroll
    for (int kk = 0; kk < 4; ++kk) {
        const int g = kk * 4 + quad;
#pragma unroll
        for (int nt = 0; nt < 8; ++nt) {
            int p = nt * 16 + m16;
            bf16x8 bf = *(const bf16x8*)(&Bt[p * 128 + ((g ^ (p & 15)) << 3)]);
            acc[nt] = MFMA16(afr[kk], bf, acc[nt]);
        }
    }

    float bv[4];
#pragma unroll
    for (int r = 0; r < 4; ++r) bv[r] = bias[cg * 128 + wave * 16 + quad * 4 + r];

    u16* ob = out1 + (((size_t)(b * 384 + cg * 128)) << 14) + (h << 7);

    // --- half 0: waves 0..3 stage co 0..63, all threads write out ---
    if (wave < 4) {
#pragma unroll
        for (int nt = 0; nt < 8; ++nt) {
            int p = nt * 16 + m16;
#pragma unroll
            for (int r = 0; r < 4; ++r)
                Cs[(wave * 16 + quad * 4 + r) * 136 + p] = f2bf(acc[nt][r] + bv[r]);
        }
    }
    __syncthreads();
#pragma unroll
    for (int it = 0; it < 2; ++it) {
        int idx = it * 512 + t;
        int co = idx >> 4, cp = idx & 15;
        *(uint4*)(&ob[((size_t)co << 14) + cp * 8]) = *(const uint4*)(&Cs[co * 136 + cp * 8]);
    }
    __syncthreads();

    // --- half 1: waves 4..7 stage co 64..127 ---
    if (wave >= 4) {
#pragma unroll
        for (int nt = 0; nt < 8; ++nt) {
            int p = nt * 16 + m16;
#pragma unroll
            for (int r = 0; r < 4; ++r)
                Cs[((wave - 4) * 16 + quad * 4 + r) * 136 + p] = f2bf(acc[nt][r] + bv[r]);
        }
    }
    __syncthreads();
    u16* ob2 = ob + ((size_t)64 << 14);
#pragma unroll
    for (int it = 0; it < 2; ++it) {
        int idx = it * 512 + t;
        int co = idx >> 4, cp = idx & 15;
        *(uint4*)(&ob2[((size_t)co << 14) + cp * 8]) = *(const uint4*)(&Cs[co * 136 + cp * 8]);
    }
}

// ---------------------------------------------------------------------------
// K3 v3: per-(b,ch) attention with the depthwise 3x3 FUSED in.
// Reads raw qkv (pre-dw); applies the 3x3 + bias on-the-fly:
//   - V: staged raw into LDS [128][144] (aliases Qt/Kt space), each lane
//     computes its dw'd vfr fragments directly.
//   - Q/K: staging loads 18 rows (+/-1 halo) per phase; the gather-transpose
//     computes the 9-tap conv per column before ssq/normalization.
// Numerics identical to the separate-k_dw version (same bf16 rounding points).
// 512 thr / 8 waves, 79 KB LDS -> 2 blocks/CU.
// ---------------------------------------------------------------------------
__global__ __launch_bounds__(512, 4) void k_attn(const u16* __restrict__ qkv,
                                                 const float* __restrict__ dww,
                                                 const float* __restrict__ dwb,
                                                 const float* __restrict__ temp,
                                                 u16* __restrict__ outp) {
    extern __shared__ char smem[];
    u16* Qt = (u16*)smem;                  // [j][i] swizzled; Pt aliases
    u16* Kt = Qt + 16384;                  // [k][i] swizzled; Osh aliases
    u16* Vr = (u16*)smem;                  // [128][144] raw V (aliases Qt/Kt)
    u16* Sg2 = Qt + 32768;                 // [2][18][144] staging = 10368 B
    float* ps = (float*)(smem + 75904);    // [4][128]
    float* rq = (float*)(smem + 77952);    // [128]
    float* rk = (float*)(smem + 78464);    // [128]
    u16* Pt = Qt;
    u16* Osh = Kt;

    const int ch = blockIdx.x, b = blockIdx.y;
    const int head = ch >> 5;
    const int t = threadIdx.x;
    const size_t qoff = ((size_t)(b * 384 + ch)) << 14;
    const size_t koff = qoff + ((size_t)128 << 14);
    const size_t voff = qoff + ((size_t)256 << 14);

    const int wave = t >> 6, lane = t & 63, m16 = lane & 15, quad = lane >> 4;

    // ---- phase V: stage raw V plane, compute dw'd vfr in registers ----
#pragma unroll
    for (int i = 0; i < 4; ++i) {
        int idx = i * 512 + t;
        int r = idx >> 4, c16 = idx & 15;
        *(uint4*)(&Vr[r * 144 + 8 + c16 * 8]) =
            *(const uint4*)(&qkv[voff + ((size_t)r << 7) + c16 * 8]);
    }
    if (t < 256) {
        int r = t >> 1, side = t & 1;
        uint4 z = {0, 0, 0, 0};
        *(uint4*)(&Vr[r * 144 + side * 136]) = z;
    } else if (t < 328) {
        int i = t - 256;
        int row = i >> 1, side = i & 1;    // 36 rows of Sg2 halo cols
        uint4 z = {0, 0, 0, 0};
        *(uint4*)(&Sg2[row * 144 + side * 136]) = z;
    }
    __syncthreads();

    bf16x8 vfr[4];
    {
        float wv9[9];
        const float* wp = dww + (size_t)(256 + ch) * 9;
#pragma unroll
        for (int i = 0; i < 9; ++i) wv9[i] = wp[i];
        const float bvv = dwb[256 + ch];
        const int r = wave * 16 + m16;
#pragma unroll
        for (int kk = 0; kk < 4; ++kk) {
            const int c0 = quad * 8 + kk * 32;
            float acc[8];
#pragma unroll
            for (int c = 0; c < 8; ++c) acc[c] = bvv;
#pragma unroll
            for (int dy = 0; dy < 3; ++dy) {
                int rr = r + dy - 1;
                float v[10];
                if ((unsigned)rr < 128u) {
                    const u16* row = &Vr[rr * 144 + 8 + c0];
                    v[0] = bf2f(row[-1]);
                    uint4 m = *(const uint4*)row;
                    v[1] = bf2f((u16)(m.x & 0xffff)); v[2] = bf2f((u16)(m.x >> 16));
                    v[3] = bf2f((u16)(m.y & 0xffff)); v[4] = bf2f((u16)(m.y >> 16));
                    v[5] = bf2f((u16)(m.z & 0xffff)); v[6] = bf2f((u16)(m.z >> 16));
                    v[7] = bf2f((u16)(m.w & 0xffff)); v[8] = bf2f((u16)(m.w >> 16));
                    v[9] = bf2f(row[8]);
                } else {
#pragma unroll
                    for (int i = 0; i < 10; ++i) v[i] = 0.f;
                }
#pragma unroll
                for (int dx = 0; dx < 3; ++dx) {
                    const float wv = wv9[dy * 3 + dx];
#pragma unroll
                    for (int c = 0; c < 8; ++c) acc[c] += wv * v[c + dx];
                }
            }
            bf16x8 a;
#pragma unroll
            for (int c = 0; c < 8; ++c) a[c] = (short)f2bf(acc[c]);
            vfr[kk] = a;
        }
    }
    __syncthreads();   // Vr dead; Qt/Kt region now reusable

    // ---- phases Q/K: stage 18 raw rows per matrix, dw in the gather ----
    const int gmat = t >> 8, gig = (t >> 7) & 1, gj = t & 127;
    u16* gdstbase = (gmat ? Kt : Qt) + gj * 128;
    float wg9[9];
    {
        const float* wp = dww + (size_t)((gmat ? 128 : 0) + ch) * 9;
#pragma unroll
        for (int i = 0; i < 9; ++i) wg9[i] = wp[i];
    }
    const float gb = dwb[(gmat ? 128 : 0) + ch];
    const size_t moff = gmat ? koff : qoff;
    float ssq = 0.f;

    for (int p = 0; p < 8; ++p) {
#pragma unroll
        for (int s0 = 0; s0 < 2; ++s0) {
            int s = s0 * 512 + t;
            if (s < 576) {
                int m = (s >= 288) ? 1 : 0;
                int within = s - m * 288;
                int lr = within >> 4, c16 = within & 15;
                int hh = p * 16 - 1 + lr;
                uint4 v = {0, 0, 0, 0};
                if ((unsigned)hh < 128u)
                    v = *(const uint4*)(&qkv[(m ? koff : qoff) + ((size_t)hh << 7) + c16 * 8]);
                *(uint4*)(&Sg2[(m * 18 + lr) * 144 + 8 + c16 * 8]) = v;
            }
        }
        __syncthreads();

        // 8 dw'd values of column gj, rows p*16 + gig*8 + 0..7
        const u16* colp = &Sg2[(gmat * 18 + gig * 8) * 144 + 8 + gj];
        float cm[10], cc[10], cp_[10];
#pragma unroll
        for (int lr = 0; lr < 10; ++lr) {
            const u16* rp = colp + lr * 144;
            cm[lr] = bf2f(rp[-1]);
            cc[lr] = bf2f(rp[0]);
            cp_[lr] = bf2f(rp[1]);
        }
        u16 tmp[8];
#pragma unroll
        for (int c = 0; c < 8; ++c) {
            float acc = gb;
#pragma unroll
            for (int dy = 0; dy < 3; ++dy)
                acc += wg9[dy * 3 + 0] * cm[c + dy] + wg9[dy * 3 + 1] * cc[c + dy] +
                       wg9[dy * 3 + 2] * cp_[c + dy];
            u16 uv = f2bf(acc);
            tmp[c] = uv;
            float f = bf2f(uv);
            ssq += f * f;
        }
        int g = p * 2 + gig;
        *(uint4*)(gdstbase + ((g ^ (gj & 15)) << 3)) = *(const uint4*)tmp;
        __syncthreads();
    }
    (void)moff;

    ps[(gmat * 2 + gig) * 128 + gj] = ssq;
    __syncthreads();
    if (t < 256) {
        int mat = t >> 7, j = t & 127;
        float s = ps[(mat * 2) * 128 + j] + ps[(mat * 2 + 1) * 128 + j];
        float r = 1.0f / fmaxf(sqrtf(s), 1e-12f);
        if (mat == 0) rq[j] = r; else rk[j] = r;
    }
    __syncthreads();

    f32x4 S[8] = {};
#pragma unroll
    for (int kk = 0; kk < 4; ++kk) {
        const int sw = ((kk * 4 + quad) ^ m16) << 3;
        bf16x8 bf = *(const bf16x8*)(&Kt[(wave * 16 + m16) * 128 + sw]);
#pragma unroll
        for (int jt = 0; jt < 8; ++jt) {
            bf16x8 af = *(const bf16x8*)(&Qt[(jt * 16 + m16) * 128 + sw]);
            S[jt] = MFMA16(af, bf, S[jt]);
        }
    }

    const float sc = temp[head] * rk[wave * 16 + m16];
    float vals[8][4];
    float vmax = -1e30f;
#pragma unroll
    for (int jt = 0; jt < 8; ++jt)
#pragma unroll
        for (int r = 0; r < 4; ++r) {
            float v = S[jt][r] * (rq[jt * 16 + quad * 4 + r] * sc);
            vals[jt][r] = v;
            vmax = fmaxf(vmax, v);
        }
    vmax = fmaxf(vmax, __shfl_xor(vmax, 16));
    vmax = fmaxf(vmax, __shfl_xor(vmax, 32));
    float sum = 0.f;
#pragma unroll
    for (int jt = 0; jt < 8; ++jt)
#pragma unroll
        for (int r = 0; r < 4; ++r) {
            float e = __expf(vals[jt][r] - vmax);
            vals[jt][r] = e;
            sum += e;
        }
    sum += __shfl_xor(sum, 16);
    sum += __shfl_xor(sum, 32);
    const float inv = 1.0f / sum;

    __syncthreads();

    {
        const int k = wave * 16 + m16;
        u16* prow = Pt + k * 128;
#pragma unroll
        for (int jt = 0; jt < 8; ++jt)
#pragma unroll
            for (int pr = 0; pr < 2; ++pr) {
                int j0 = jt * 16 + quad * 4 + pr * 2;
                u32 pk = (u32)f2bf(vals[jt][pr * 2] * inv) |
                         ((u32)f2bf(vals[jt][pr * 2 + 1] * inv) << 16);
                *(u32*)(prow + (((j0 >> 3) ^ (k & 15)) << 3) + (j0 & 7)) = pk;
            }
    }
    __syncthreads();

    f32x4 O[8] = {};
#pragma unroll
    for (int kk = 0; kk < 4; ++kk) {
        const int sw = ((kk * 4 + quad) ^ m16) << 3;
#pragma unroll
        for (int nt = 0; nt < 8; ++nt) {
            bf16x8 bf = *(const bf16x8*)(&Pt[(nt * 16 + m16) * 128 + sw]);
            O[nt] = MFMA16(vfr[kk], bf, O[nt]);
        }
    }

#pragma unroll
    for (int nt = 0; nt < 8; ++nt) {
        int k = nt * 16 + m16;
#pragma unroll
        for (int r = 0; r < 4; ++r) {
            int i = wave * 16 + quad * 4 + r;
            Osh[i * 128 + (((k >> 3) ^ (i & 15)) << 3) + (k & 7)] = f2bf(O[nt][r]);
        }
    }
    __syncthreads();

    u16* ob = outp + (((size_t)(b * 128 + ch)) << 14);
#pragma unroll
    for (int it = 0; it < 4; ++it) {
        int idx = it * 512 + t;
        int row = idx >> 4, gk = idx & 15;
        uint4 v = *(const uint4*)(&Osh[row * 128 + ((gk ^ (row & 15)) << 3)]);
        *(uint4*)(&ob[(row << 7) + gk * 8]) = v;
    }
}

// ---------------------------------------------------------------------------
// K4 v2: proj 1x1 conv.  Staged-panel gather transpose + direct fp32 stores.
// ---------------------------------------------------------------------------
__global__ __launch_bounds__(512, 6) void k_proj(const u16* __restrict__ ain,
                                                 const float* __restrict__ w,
                                                 const float* __restrict__ bias,
                                                 float* __restrict__ outp) {
    extern __shared__ char smem[];
    u16* Bt = (u16*)smem;            // 32 KB swizzled [p][g]
    u16* Sg = Bt + 16384;            // [32][144] staging (9 KB)
    const int h = blockIdx.x, b = blockIdx.y;
    const int t = threadIdx.x;

    const int ldr = t >> 4, ldj8 = t & 15;
    const int gig = t >> 7, gp = t & 127;
    const u16* gcol = &Sg[(gig * 8) * 144 + gp];
    u16* gdst = Bt + gp * 128;
#pragma unroll
    for (int ph = 0; ph < 4; ++ph) {
        int ch = ph * 32 + ldr;
        *(uint4*)(&Sg[ldr * 144 + ldj8 * 8]) =
            *(const uint4*)(&ain[(((size_t)(b * 128 + ch)) << 14) + (h << 7) + ldj8 * 8]);
        __syncthreads();
        u16 tmp[8];
#pragma unroll
        for (int c = 0; c < 8; ++c) tmp[c] = gcol[c * 144];
        int g = ph * 4 + gig;
        *(uint4*)(gdst + ((g ^ (gp & 15)) << 3)) = *(const uint4*)tmp;
        __syncthreads();
    }

    const int wave = t >> 6, lane = t & 63, m16 = lane & 15, quad = lane >> 4;
    bf16x8 afr[4];
    {
        const float* wp0 = w + (size_t)(wave * 16 + m16) * 128 + quad * 8;
#pragma unroll
        for (int kk = 0; kk < 4; ++kk) {
            float4 w0 = *(const float4*)(wp0 + kk * 32);
            float4 w1 = *(const float4*)(wp0 + kk * 32 + 4);
            bf16x8 a;
            a[0] = (short)f2bf(w0.x); a[1] = (short)f2bf(w0.y);
            a[2] = (short)f2bf(w0.z); a[3] = (short)f2bf(w0.w);
            a[4] = (short)f2bf(w1.x); a[5] = (short)f2bf(w1.y);
            a[6] = (short)f2bf(w1.z); a[7] = (short)f2bf(w1.w);
            afr[kk] = a;
        }
    }

    f32x4 acc[8] = {};
#pragma unroll
    for (int kk = 0; kk < 4; ++kk) {
        const int g = kk * 4 + quad;
#pragma unroll
        for (int nt = 0; nt < 8; ++nt) {
            int p = nt * 16 + m16;
            bf16x8 bf = *(const bf16x8*)(&Bt[p * 128 + ((g ^ (p & 15)) << 3)]);
            acc[nt] = MFMA16(afr[kk], bf, acc[nt]);
        }
    }

    float bv[4];
#pragma unroll
    for (int r = 0; r < 4; ++r) bv[r] = bias[wave * 16 + quad * 4 + r];
    float* ob = outp + (((size_t)(b * 128)) << 14) + (h << 7);
#pragma unroll
    for (int nt = 0; nt < 8; ++nt) {
        int p = nt * 16 + m16;
#pragma unroll
        for (int r = 0; r < 4; ++r) {
            int co = wave * 16 + quad * 4 + r;
            ob[((size_t)co << 14) + p] = acc[nt][r] + bv[r];
        }
    }
}

// ---------------------------------------------------------------------------
extern "C" void kernel_launch(void* const* d_in, const int* in_sizes, int n_in,
                              void* d_out, int out_size, void* d_ws, size_t ws_size,
                              hipStream_t stream) {
    const float* x      = (const float*)d_in[0];
    const float* qkv_w  = (const float*)d_in[1];
    const float* qkv_b  = (const float*)d_in[2];
    const float* dw_w   = (const float*)d_in[3];
    const float* dw_b   = (const float*)d_in[4];
    const float* proj_w = (const float*)d_in[5];
    const float* proj_b = (const float*)d_in[6];
    const float* temp   = (const float*)d_in[7];
    float* out = (float*)d_out;

    u16* buf1 = (u16*)d_ws;
    u16* buf2 = buf1 + (size_t)8 * 384 * 16384;

    hipFuncSetAttribute((const void*)k_qkv,  hipFuncAttributeMaxDynamicSharedMemorySize, 50176);
    hipFuncSetAttribute((const void*)k_attn, hipFuncAttributeMaxDynamicSharedMemorySize, 78976);
    hipFuncSetAttribute((const void*)k_proj, hipFuncAttributeMaxDynamicSharedMemorySize, 41984);

    k_xpose<<<dim3(128, 8), 256, 0, stream>>>(x, buf2);
    k_qkv<<<dim3(128, 3, 8), 512, 50176, stream>>>(buf2, qkv_w, qkv_b, buf1);
    k_attn<<<dim3(128, 8), 512, 78976, stream>>>(buf1, dw_w, dw_b, temp, buf2);
    k_proj<<<dim3(128, 8), 512, 41984, stream>>>(buf2, proj_w, proj_b, out);
}

// Round 2
// 285.356 us; speedup vs baseline: 1.5513x; 1.5513x over previous
//
#include <hip/hip_runtime.h>

typedef unsigned short u16;
typedef unsigned int   u32;

typedef short bf16x8 __attribute__((ext_vector_type(8)));
typedef float f32x4  __attribute__((ext_vector_type(4)));

__device__ __forceinline__ float bf2f(u16 u) { return __uint_as_float(((u32)u) << 16); }
__device__ __forceinline__ u16 f2bf(float f) {
    u32 u = __float_as_uint(f);
    return (u16)((u + 0x7fffu + ((u >> 16) & 1u)) >> 16);
}

#define MFMA16(a, b, c) __builtin_amdgcn_mfma_f32_16x16x32_bf16(a, b, c, 0, 0, 0)

// ---------------------------------------------------------------------------
// K0: transpose x[b][ci][p] fp32 -> xT[b][p][ci] bf16.
// ---------------------------------------------------------------------------
__global__ __launch_bounds__(256, 4) void k_xpose(const float* __restrict__ x,
                                                  u16* __restrict__ xT) {
    __shared__ u16 Xs[128 * 128];
    const int ptile = blockIdx.x, b = blockIdx.y;
    const int t = threadIdx.x;
    const float* xb = x + (((size_t)b) << 21) + ptile * 128;
#pragma unroll
    for (int i = 0; i < 16; ++i) {
        int idx = i * 256 + t;
        int ci = idx >> 5, pq = idx & 31;
        float4 v = *(const float4*)(xb + (((size_t)ci) << 14) + pq * 4);
        u32 lo = (u32)f2bf(v.x) | ((u32)f2bf(v.y) << 16);
        u32 hi = (u32)f2bf(v.z) | ((u32)f2bf(v.w) << 16);
        uint2 pk; pk.x = lo; pk.y = hi;
        int cq = ci >> 3;
        *(uint2*)(&Xs[ci * 128 + ((pq ^ cq) << 2)]) = pk;
    }
    __syncthreads();
    u16* ob = xT + (((size_t)b) << 21) + ((size_t)(ptile * 128)) * 128;
#pragma unroll
    for (int j = 0; j < 8; ++j) {
        int p = j * 16 + (t >> 4), cq = t & 15;
        u16 tmp[8];
#pragma unroll
        for (int c = 0; c < 8; ++c) {
            int ci = cq * 8 + c;
            tmp[c] = Xs[ci * 128 + (((p >> 2) ^ cq) << 2) + (p & 3)];
        }
        *(uint4*)(&ob[(size_t)p * 128 + cq * 8]) = *(const uint4*)tmp;
    }
}

// ---------------------------------------------------------------------------
// K1 v3: qkv 1x1 conv from xT (block = (h, cg, b)), Cs staged in two
// co-halves -> LDS 49 KB -> 3 blocks/CU.
// ---------------------------------------------------------------------------
__global__ __launch_bounds__(512, 6) void k_qkv(const u16* __restrict__ xT,
                                                const float* __restrict__ w,
                                                const float* __restrict__ bias,
                                                u16* __restrict__ out1) {
    extern __shared__ char smem[];
    u16* Bt = (u16*)smem;            // 32 KB swizzled [p][g]
    u16* Cs = Bt + 2048 * 8;         // [64 co][136 p] = 17 KB
    const int h = blockIdx.x, cg = blockIdx.y, b = blockIdx.z;
    const int t = threadIdx.x;

    const u16* xb = xT + (((size_t)b) << 21) + ((size_t)(h * 128)) * 128;
#pragma unroll
    for (int i = 0; i < 4; ++i) {
        int slot = i * 512 + t;
        int p = slot >> 4, g = slot & 15;
        int gg = g ^ (p & 15);
        uint4 v = *(const uint4*)(&xb[p * 128 + gg * 8]);
        *(uint4*)(&Bt[slot * 8]) = v;
    }

    const int wave = t >> 6, lane = t & 63, m16 = lane & 15, quad = lane >> 4;
    bf16x8 afr[4];
    {
        const float* wp0 = w + (size_t)(cg * 128 + wave * 16 + m16) * 128 + quad * 8;
#pragma unroll
        for (int kk = 0; kk < 4; ++kk) {
            float4 w0 = *(const float4*)(wp0 + kk * 32);
            float4 w1 = *(const float4*)(wp0 + kk * 32 + 4);
            bf16x8 a;
            a[0] = (short)f2bf(w0.x); a[1] = (short)f2bf(w0.y);
            a[2] = (short)f2bf(w0.z); a[3] = (short)f2bf(w0.w);
            a[4] = (short)f2bf(w1.x); a[5] = (short)f2bf(w1.y);
            a[6] = (short)f2bf(w1.z); a[7] = (short)f2bf(w1.w);
            afr[kk] = a;
        }
    }
    __syncthreads();

    f32x4 acc[8] = {};
#pragma unroll
    for (int kk = 0; kk < 4; ++kk) {
        const int g = kk * 4 + quad;
#pragma unroll
        for (int nt = 0; nt < 8; ++nt) {
            int p = nt * 16 + m16;
            bf16x8 bf = *(const bf16x8*)(&Bt[p * 128 + ((g ^ (p & 15)) << 3)]);
            acc[nt] = MFMA16(afr[kk], bf, acc[nt]);
        }
    }

    float bv[4];
#pragma unroll
    for (int r = 0; r < 4; ++r) bv[r] = bias[cg * 128 + wave * 16 + quad * 4 + r];

    u16* ob = out1 + (((size_t)(b * 384 + cg * 128)) << 14) + (h << 7);

    // --- half 0: waves 0..3 stage co 0..63, all threads write out ---
    if (wave < 4) {
#pragma unroll
        for (int nt = 0; nt < 8; ++nt) {
            int p = nt * 16 + m16;
#pragma unroll
            for (int r = 0; r < 4; ++r)
                Cs[(wave * 16 + quad * 4 + r) * 136 + p] = f2bf(acc[nt][r] + bv[r]);
        }
    }
    __syncthreads();
#pragma unroll
    for (int it = 0; it < 2; ++it) {
        int idx = it * 512 + t;
        int co = idx >> 4, cp = idx & 15;
        *(uint4*)(&ob[((size_t)co << 14) + cp * 8]) = *(const uint4*)(&Cs[co * 136 + cp * 8]);
    }
    __syncthreads();

    // --- half 1: waves 4..7 stage co 64..127 ---
    if (wave >= 4) {
#pragma unroll
        for (int nt = 0; nt < 8; ++nt) {
            int p = nt * 16 + m16;
#pragma unroll
            for (int r = 0; r < 4; ++r)
                Cs[((wave - 4) * 16 + quad * 4 + r) * 136 + p] = f2bf(acc[nt][r] + bv[r]);
        }
    }
    __syncthreads();
    u16* ob2 = ob + ((size_t)64 << 14);
#pragma unroll
    for (int it = 0; it < 2; ++it) {
        int idx = it * 512 + t;
        int co = idx >> 4, cp = idx & 15;
        *(uint4*)(&ob2[((size_t)co << 14) + cp * 8]) = *(const uint4*)(&Cs[co * 136 + cp * 8]);
    }
}

// ---------------------------------------------------------------------------
// K3 v4: fused dw3x3 + attention, register-pressure-fixed.
//   - V: staged raw into LDS (aliases Qt/Kt), dw'd into vfr in registers.
//   - Q/K: 18-row halo staging per phase; dw via ROLLING 3-tap window
//     (acc[8] + 3 temps live, not 30), phase loop forced unroll 1 so the
//     compiler cannot pipeline 8 phases into one giant live range.
// Numerics identical to the separate-k_dw version.
// ---------------------------------------------------------------------------
__global__ __launch_bounds__(512, 4) void k_attn(const u16* __restrict__ qkv,
                                                 const float* __restrict__ dww,
                                                 const float* __restrict__ dwb,
                                                 const float* __restrict__ temp,
                                                 u16* __restrict__ outp) {
    extern __shared__ char smem[];
    u16* Qt = (u16*)smem;                  // [j][i] swizzled; Pt aliases
    u16* Kt = Qt + 16384;                  // [k][i] swizzled; Osh aliases
    u16* Vr = (u16*)smem;                  // [128][144] raw V (aliases Qt+Kt head)
    u16* Sg2 = Qt + 32768;                 // [2][18][144] staging = 10368 B
    float* ps = (float*)(smem + 75904);    // [4][128]
    float* rq = (float*)(smem + 77952);    // [128]
    float* rk = (float*)(smem + 78464);    // [128]
    u16* Pt = Qt;
    u16* Osh = Kt;

    const int ch = blockIdx.x, b = blockIdx.y;
    const int head = ch >> 5;
    const int t = threadIdx.x;
    const size_t qoff = ((size_t)(b * 384 + ch)) << 14;
    const size_t koff = qoff + ((size_t)128 << 14);
    const size_t voff = qoff + ((size_t)256 << 14);

    const int wave = t >> 6, lane = t & 63, m16 = lane & 15, quad = lane >> 4;

    // ---- phase V: stage raw V plane, compute dw'd vfr in registers ----
#pragma unroll
    for (int i = 0; i < 4; ++i) {
        int idx = i * 512 + t;
        int r = idx >> 4, c16 = idx & 15;
        *(uint4*)(&Vr[r * 144 + 8 + c16 * 8]) =
            *(const uint4*)(&qkv[voff + ((size_t)r << 7) + c16 * 8]);
    }
    if (t < 256) {
        int r = t >> 1, side = t & 1;
        uint4 z = {0, 0, 0, 0};
        *(uint4*)(&Vr[r * 144 + side * 136]) = z;
    } else if (t < 328) {
        int i = t - 256;
        int row = i >> 1, side = i & 1;    // 36 rows of Sg2 halo cols
        uint4 z = {0, 0, 0, 0};
        *(uint4*)(&Sg2[row * 144 + side * 136]) = z;
    }
    __syncthreads();

    bf16x8 vfr[4];
    {
        float wv9[9];
        const float* wp = dww + (size_t)(256 + ch) * 9;
#pragma unroll
        for (int i = 0; i < 9; ++i) wv9[i] = wp[i];
        const float bvv = dwb[256 + ch];
        const int r = wave * 16 + m16;
#pragma unroll
        for (int kk = 0; kk < 4; ++kk) {
            const int c0 = quad * 8 + kk * 32;
            float acc[8];
#pragma unroll
            for (int c = 0; c < 8; ++c) acc[c] = bvv;
#pragma unroll
            for (int dy = 0; dy < 3; ++dy) {
                int rr = r + dy - 1;
                if ((unsigned)rr < 128u) {
                    const u16* row = &Vr[rr * 144 + 8 + c0];
                    float v0 = bf2f(row[-1]);
                    uint4 m = *(const uint4*)row;
                    float v1 = bf2f((u16)(m.x & 0xffff)), v2 = bf2f((u16)(m.x >> 16));
                    float v3 = bf2f((u16)(m.y & 0xffff)), v4 = bf2f((u16)(m.y >> 16));
                    float v5 = bf2f((u16)(m.z & 0xffff)), v6 = bf2f((u16)(m.z >> 16));
                    float v7 = bf2f((u16)(m.w & 0xffff)), v8 = bf2f((u16)(m.w >> 16));
                    float v9 = bf2f(row[8]);
                    const float w0 = wv9[dy * 3], w1 = wv9[dy * 3 + 1], w2 = wv9[dy * 3 + 2];
                    acc[0] += w0 * v0 + w1 * v1 + w2 * v2;
                    acc[1] += w0 * v1 + w1 * v2 + w2 * v3;
                    acc[2] += w0 * v2 + w1 * v3 + w2 * v4;
                    acc[3] += w0 * v3 + w1 * v4 + w2 * v5;
                    acc[4] += w0 * v4 + w1 * v5 + w2 * v6;
                    acc[5] += w0 * v5 + w1 * v6 + w2 * v7;
                    acc[6] += w0 * v6 + w1 * v7 + w2 * v8;
                    acc[7] += w0 * v7 + w1 * v8 + w2 * v9;
                }
            }
            bf16x8 a;
#pragma unroll
            for (int c = 0; c < 8; ++c) a[c] = (short)f2bf(acc[c]);
            vfr[kk] = a;
        }
    }
    __syncthreads();   // Vr dead; Qt/Kt region now reusable

    // ---- phases Q/K: stage 18 raw rows per matrix, rolling-window dw ----
    const int gmat = t >> 8, gig = (t >> 7) & 1, gj = t & 127;
    u16* gdstbase = (gmat ? Kt : Qt) + gj * 128;
    float wg9[9];
    {
        const float* wp = dww + (size_t)((gmat ? 128 : 0) + ch) * 9;
#pragma unroll
        for (int i = 0; i < 9; ++i) wg9[i] = wp[i];
    }
    const float gb = dwb[(gmat ? 128 : 0) + ch];
    float ssq = 0.f;

#pragma unroll 1
    for (int p = 0; p < 8; ++p) {
#pragma unroll
        for (int s0 = 0; s0 < 2; ++s0) {
            int s = s0 * 512 + t;
            if (s < 576) {
                int m = (s >= 288) ? 1 : 0;
                int within = s - m * 288;
                int lr = within >> 4, c16 = within & 15;
                int hh = p * 16 - 1 + lr;
                uint4 v = {0, 0, 0, 0};
                if ((unsigned)hh < 128u)
                    v = *(const uint4*)(&qkv[(m ? koff : qoff) + ((size_t)hh << 7) + c16 * 8]);
                *(uint4*)(&Sg2[(m * 18 + lr) * 144 + 8 + c16 * 8]) = v;
            }
        }
        __syncthreads();

        // 8 dw'd values of column gj, rows p*16 + gig*8 + 0..7.
        // Rolling window: one pass over the 10 staged rows, 3 live taps.
        const u16* colp = &Sg2[(gmat * 18 + gig * 8) * 144 + 8 + gj];
        float acc[8];
#pragma unroll
        for (int c = 0; c < 8; ++c) acc[c] = gb;
#pragma unroll
        for (int lr = 0; lr < 10; ++lr) {
            const u16* rp = colp + lr * 144;
            float L = bf2f(rp[-1]);
            float C = bf2f(rp[0]);
            float R = bf2f(rp[1]);
            if (lr < 8) {
                float s0v = wg9[0] * L + wg9[1] * C + wg9[2] * R;
                acc[lr] += s0v;
            }
            if (lr >= 1 && lr <= 8) {
                float s1v = wg9[3] * L + wg9[4] * C + wg9[5] * R;
                acc[lr - 1] += s1v;
            }
            if (lr >= 2) {
                float s2v = wg9[6] * L + wg9[7] * C + wg9[8] * R;
                acc[lr - 2] += s2v;
            }
        }
        u16 tmp[8];
#pragma unroll
        for (int c = 0; c < 8; ++c) {
            u16 uv = f2bf(acc[c]);
            tmp[c] = uv;
            float f = bf2f(uv);
            ssq += f * f;
        }
        int g = p * 2 + gig;
        *(uint4*)(gdstbase + ((g ^ (gj & 15)) << 3)) = *(const uint4*)tmp;
        __syncthreads();
    }

    ps[(gmat * 2 + gig) * 128 + gj] = ssq;
    __syncthreads();
    if (t < 256) {
        int mat = t >> 7, j = t & 127;
        float s = ps[(mat * 2) * 128 + j] + ps[(mat * 2 + 1) * 128 + j];
        float r = 1.0f / fmaxf(sqrtf(s), 1e-12f);
        if (mat == 0) rq[j] = r; else rk[j] = r;
    }
    __syncthreads();

    f32x4 S[8] = {};
#pragma unroll
    for (int kk = 0; kk < 4; ++kk) {
        const int sw = ((kk * 4 + quad) ^ m16) << 3;
        bf16x8 bf = *(const bf16x8*)(&Kt[(wave * 16 + m16) * 128 + sw]);
#pragma unroll
        for (int jt = 0; jt < 8; ++jt) {
            bf16x8 af = *(const bf16x8*)(&Qt[(jt * 16 + m16) * 128 + sw]);
            S[jt] = MFMA16(af, bf, S[jt]);
        }
    }

    const float sc = temp[head] * rk[wave * 16 + m16];
    float vals[8][4];
    float vmax = -1e30f;
#pragma unroll
    for (int jt = 0; jt < 8; ++jt)
#pragma unroll
        for (int r = 0; r < 4; ++r) {
            float v = S[jt][r] * (rq[jt * 16 + quad * 4 + r] * sc);
            vals[jt][r] = v;
            vmax = fmaxf(vmax, v);
        }
    vmax = fmaxf(vmax, __shfl_xor(vmax, 16));
    vmax = fmaxf(vmax, __shfl_xor(vmax, 32));
    float sum = 0.f;
#pragma unroll
    for (int jt = 0; jt < 8; ++jt)
#pragma unroll
        for (int r = 0; r < 4; ++r) {
            float e = __expf(vals[jt][r] - vmax);
            vals[jt][r] = e;
            sum += e;
        }
    sum += __shfl_xor(sum, 16);
    sum += __shfl_xor(sum, 32);
    const float inv = 1.0f / sum;

    __syncthreads();

    {
        const int k = wave * 16 + m16;
        u16* prow = Pt + k * 128;
#pragma unroll
        for (int jt = 0; jt < 8; ++jt)
#pragma unroll
            for (int pr = 0; pr < 2; ++pr) {
                int j0 = jt * 16 + quad * 4 + pr * 2;
                u32 pk = (u32)f2bf(vals[jt][pr * 2] * inv) |
                         ((u32)f2bf(vals[jt][pr * 2 + 1] * inv) << 16);
                *(u32*)(prow + (((j0 >> 3) ^ (k & 15)) << 3) + (j0 & 7)) = pk;
            }
    }
    __syncthreads();

    f32x4 O[8] = {};
#pragma unroll
    for (int kk = 0; kk < 4; ++kk) {
        const int sw = ((kk * 4 + quad) ^ m16) << 3;
#pragma unroll
        for (int nt = 0; nt < 8; ++nt) {
            bf16x8 bf = *(const bf16x8*)(&Pt[(nt * 16 + m16) * 128 + sw]);
            O[nt] = MFMA16(vfr[kk], bf, O[nt]);
        }
    }

#pragma unroll
    for (int nt = 0; nt < 8; ++nt) {
        int k = nt * 16 + m16;
#pragma unroll
        for (int r = 0; r < 4; ++r) {
            int i = wave * 16 + quad * 4 + r;
            Osh[i * 128 + (((k >> 3) ^ (i & 15)) << 3) + (k & 7)] = f2bf(O[nt][r]);
        }
    }
    __syncthreads();

    u16* ob = outp + (((size_t)(b * 128 + ch)) << 14);
#pragma unroll
    for (int it = 0; it < 4; ++it) {
        int idx = it * 512 + t;
        int row = idx >> 4, gk = idx & 15;
        uint4 v = *(const uint4*)(&Osh[row * 128 + ((gk ^ (row & 15)) << 3)]);
        *(uint4*)(&ob[(row << 7) + gk * 8]) = v;
    }
}

// ---------------------------------------------------------------------------
// K4 v2: proj 1x1 conv.  Staged-panel gather transpose + direct fp32 stores.
// ---------------------------------------------------------------------------
__global__ __launch_bounds__(512, 6) void k_proj(const u16* __restrict__ ain,
                                                 const float* __restrict__ w,
                                                 const float* __restrict__ bias,
                                                 float* __restrict__ outp) {
    extern __shared__ char smem[];
    u16* Bt = (u16*)smem;            // 32 KB swizzled [p][g]
    u16* Sg = Bt + 16384;            // [32][144] staging (9 KB)
    const int h = blockIdx.x, b = blockIdx.y;
    const int t = threadIdx.x;

    const int ldr = t >> 4, ldj8 = t & 15;
    const int gig = t >> 7, gp = t & 127;
    const u16* gcol = &Sg[(gig * 8) * 144 + gp];
    u16* gdst = Bt + gp * 128;
#pragma unroll
    for (int ph = 0; ph < 4; ++ph) {
        int ch = ph * 32 + ldr;
        *(uint4*)(&Sg[ldr * 144 + ldj8 * 8]) =
            *(const uint4*)(&ain[(((size_t)(b * 128 + ch)) << 14) + (h << 7) + ldj8 * 8]);
        __syncthreads();
        u16 tmp[8];
#pragma unroll
        for (int c = 0; c < 8; ++c) tmp[c] = gcol[c * 144];
        int g = ph * 4 + gig;
        *(uint4*)(gdst + ((g ^ (gp & 15)) << 3)) = *(const uint4*)tmp;
        __syncthreads();
    }

    const int wave = t >> 6, lane = t & 63, m16 = lane & 15, quad = lane >> 4;
    bf16x8 afr[4];
    {
        const float* wp0 = w + (size_t)(wave * 16 + m16) * 128 + quad * 8;
#pragma unroll
        for (int kk = 0; kk < 4; ++kk) {
            float4 w0 = *(const float4*)(wp0 + kk * 32);
            float4 w1 = *(const float4*)(wp0 + kk * 32 + 4);
            bf16x8 a;
            a[0] = (short)f2bf(w0.x); a[1] = (short)f2bf(w0.y);
            a[2] = (short)f2bf(w0.z); a[3] = (short)f2bf(w0.w);
            a[4] = (short)f2bf(w1.x); a[5] = (short)f2bf(w1.y);
            a[6] = (short)f2bf(w1.z); a[7] = (short)f2bf(w1.w);
            afr[kk] = a;
        }
    }

    f32x4 acc[8] = {};
#pragma unroll
    for (int kk = 0; kk < 4; ++kk) {
        const int g = kk * 4 + quad;
#pragma unroll
        for (int nt = 0; nt < 8; ++nt) {
            int p = nt * 16 + m16;
            bf16x8 bf = *(const bf16x8*)(&Bt[p * 128 + ((g ^ (p & 15)) << 3)]);
            acc[nt] = MFMA16(afr[kk], bf, acc[nt]);
        }
    }

    float bv[4];
#pragma unroll
    for (int r = 0; r < 4; ++r) bv[r] = bias[wave * 16 + quad * 4 + r];
    float* ob = outp + (((size_t)(b * 128)) << 14) + (h << 7);
#pragma unroll
    for (int nt = 0; nt < 8; ++nt) {
        int p = nt * 16 + m16;
#pragma unroll
        for (int r = 0; r < 4; ++r) {
            int co = wave * 16 + quad * 4 + r;
            ob[((size_t)co << 14) + p] = acc[nt][r] + bv[r];
        }
    }
}

// ---------------------------------------------------------------------------
extern "C" void kernel_launch(void* const* d_in, const int* in_sizes, int n_in,
                              void* d_out, int out_size, void* d_ws, size_t ws_size,
                              hipStream_t stream) {
    const float* x      = (const float*)d_in[0];
    const float* qkv_w  = (const float*)d_in[1];
    const float* qkv_b  = (const float*)d_in[2];
    const float* dw_w   = (const float*)d_in[3];
    const float* dw_b   = (const float*)d_in[4];
    const float* proj_w = (const float*)d_in[5];
    const float* proj_b = (const float*)d_in[6];
    const float* temp   = (const float*)d_in[7];
    float* out = (float*)d_out;

    u16* buf1 = (u16*)d_ws;
    u16* buf2 = buf1 + (size_t)8 * 384 * 16384;

    hipFuncSetAttribute((const void*)k_qkv,  hipFuncAttributeMaxDynamicSharedMemorySize, 50176);
    hipFuncSetAttribute((const void*)k_attn, hipFuncAttributeMaxDynamicSharedMemorySize, 78976);
    hipFuncSetAttribute((const void*)k_proj, hipFuncAttributeMaxDynamicSharedMemorySize, 41984);

    k_xpose<<<dim3(128, 8), 256, 0, stream>>>(x, buf2);
    k_qkv<<<dim3(128, 3, 8), 512, 50176, stream>>>(buf2, qkv_w, qkv_b, buf1);
    k_attn<<<dim3(128, 8), 512, 78976, stream>>>(buf1, dw_w, dw_b, temp, buf2);
    k_proj<<<dim3(128, 8), 512, 41984, stream>>>(buf2, proj_w, proj_b, out);
}

// Round 3
// 247.988 us; speedup vs baseline: 1.7851x; 1.1507x over previous
//
#include <hip/hip_runtime.h>

typedef unsigned short u16;
typedef unsigned int   u32;

typedef short bf16x8 __attribute__((ext_vector_type(8)));
typedef float f32x4  __attribute__((ext_vector_type(4)));

__device__ __forceinline__ float bf2f(u16 u) { return __uint_as_float(((u32)u) << 16); }
__device__ __forceinline__ u16 f2bf(float f) {
    u32 u = __float_as_uint(f);
    return (u16)((u + 0x7fffu + ((u >> 16) & 1u)) >> 16);
}

#define MFMA16(a, b, c) __builtin_amdgcn_mfma_f32_16x16x32_bf16(a, b, c, 0, 0, 0)

// ---------------------------------------------------------------------------
// K0: transpose x[b][ci][p] fp32 -> xT[b][p][ci] bf16.
// ---------------------------------------------------------------------------
__global__ __launch_bounds__(256, 4) void k_xpose(const float* __restrict__ x,
                                                  u16* __restrict__ xT) {
    __shared__ u16 Xs[128 * 128];
    const int ptile = blockIdx.x, b = blockIdx.y;
    const int t = threadIdx.x;
    const float* xb = x + (((size_t)b) << 21) + ptile * 128;
#pragma unroll
    for (int i = 0; i < 16; ++i) {
        int idx = i * 256 + t;
        int ci = idx >> 5, pq = idx & 31;
        float4 v = *(const float4*)(xb + (((size_t)ci) << 14) + pq * 4);
        u32 lo = (u32)f2bf(v.x) | ((u32)f2bf(v.y) << 16);
        u32 hi = (u32)f2bf(v.z) | ((u32)f2bf(v.w) << 16);
        uint2 pk; pk.x = lo; pk.y = hi;
        int cq = ci >> 3;
        *(uint2*)(&Xs[ci * 128 + ((pq ^ cq) << 2)]) = pk;
    }
    __syncthreads();
    u16* ob = xT + (((size_t)b) << 21) + ((size_t)(ptile * 128)) * 128;
#pragma unroll
    for (int j = 0; j < 8; ++j) {
        int p = j * 16 + (t >> 4), cq = t & 15;
        u16 tmp[8];
#pragma unroll
        for (int c = 0; c < 8; ++c) {
            int ci = cq * 8 + c;
            tmp[c] = Xs[ci * 128 + (((p >> 2) ^ cq) << 2) + (p & 3)];
        }
        *(uint4*)(&ob[(size_t)p * 128 + cq * 8]) = *(const uint4*)tmp;
    }
}

// ---------------------------------------------------------------------------
// K1 v4: qkv 1x1 conv, templated on output-plane layout.
//   CM=false: block = spatial row  h; plane written row-major    [ch][h][w]
//   CM=true : block = spatial col  w; plane written column-major [ch][w][h]
// The only difference is the xT staging address; the MFMA core and the
// (fully coalesced) output write are identical.
// ---------------------------------------------------------------------------
template <bool CM>
__global__ __launch_bounds__(512, 6) void k_qkv_t(const u16* __restrict__ xT,
                                                  const float* __restrict__ w,
                                                  const float* __restrict__ bias,
                                                  u16* __restrict__ out1,
                                                  int cgbase) {
    extern __shared__ char smem[];
    u16* Bt = (u16*)smem;            // 32 KB swizzled [p][g]
    u16* Cs = Bt + 2048 * 8;         // [64 co][136 p] = 17 KB
    const int h = blockIdx.x, cg = blockIdx.y + cgbase, b = blockIdx.z;
    const int t = threadIdx.x;

    const u16* xb = xT + (((size_t)b) << 21) + (CM ? (h << 7) : (h << 14));
#pragma unroll
    for (int i = 0; i < 4; ++i) {
        int slot = i * 512 + t;
        int p = slot >> 4, g = slot & 15;
        int gg = g ^ (p & 15);
        uint4 v = *(const uint4*)(&xb[(CM ? (p << 14) : (p << 7)) + gg * 8]);
        *(uint4*)(&Bt[slot * 8]) = v;
    }

    const int wave = t >> 6, lane = t & 63, m16 = lane & 15, quad = lane >> 4;
    bf16x8 afr[4];
    {
        const float* wp0 = w + (size_t)(cg * 128 + wave * 16 + m16) * 128 + quad * 8;
#pragma unroll
        for (int kk = 0; kk < 4; ++kk) {
            float4 w0 = *(const float4*)(wp0 + kk * 32);
            float4 w1 = *(const float4*)(wp0 + kk * 32 + 4);
            bf16x8 a;
            a[0] = (short)f2bf(w0.x); a[1] = (short)f2bf(w0.y);
            a[2] = (short)f2bf(w0.z); a[3] = (short)f2bf(w0.w);
            a[4] = (short)f2bf(w1.x); a[5] = (short)f2bf(w1.y);
            a[6] = (short)f2bf(w1.z); a[7] = (short)f2bf(w1.w);
            afr[kk] = a;
        }
    }
    __syncthreads();

    f32x4 acc[8] = {};
#pragma unroll
    for (int kk = 0; kk < 4; ++kk) {
        const int g = kk * 4 + quad;
#pragma unroll
        for (int nt = 0; nt < 8; ++nt) {
            int p = nt * 16 + m16;
            bf16x8 bf = *(const bf16x8*)(&Bt[p * 128 + ((g ^ (p & 15)) << 3)]);
            acc[nt] = MFMA16(afr[kk], bf, acc[nt]);
        }
    }

    float bv[4];
#pragma unroll
    for (int r = 0; r < 4; ++r) bv[r] = bias[cg * 128 + wave * 16 + quad * 4 + r];

    u16* ob = out1 + (((size_t)(b * 384 + cg * 128)) << 14) + (h << 7);

    // --- half 0: waves 0..3 stage co 0..63, all threads write out ---
    if (wave < 4) {
#pragma unroll
        for (int nt = 0; nt < 8; ++nt) {
            int p = nt * 16 + m16;
#pragma unroll
            for (int r = 0; r < 4; ++r)
                Cs[(wave * 16 + quad * 4 + r) * 136 + p] = f2bf(acc[nt][r] + bv[r]);
        }
    }
    __syncthreads();
#pragma unroll
    for (int it = 0; it < 2; ++it) {
        int idx = it * 512 + t;
        int co = idx >> 4, cp = idx & 15;
        *(uint4*)(&ob[((size_t)co << 14) + cp * 8]) = *(const uint4*)(&Cs[co * 136 + cp * 8]);
    }
    __syncthreads();

    // --- half 1: waves 4..7 stage co 64..127 ---
    if (wave >= 4) {
#pragma unroll
        for (int nt = 0; nt < 8; ++nt) {
            int p = nt * 16 + m16;
#pragma unroll
            for (int r = 0; r < 4; ++r)
                Cs[((wave - 4) * 16 + quad * 4 + r) * 136 + p] = f2bf(acc[nt][r] + bv[r]);
        }
    }
    __syncthreads();
    u16* ob2 = ob + ((size_t)64 << 14);
#pragma unroll
    for (int it = 0; it < 2; ++it) {
        int idx = it * 512 + t;
        int co = idx >> 4, cp = idx & 15;
        *(uint4*)(&ob2[((size_t)co << 14) + cp * 8]) = *(const uint4*)(&Cs[co * 136 + cp * 8]);
    }
}

// ---------------------------------------------------------------------------
// K3 v5: fused dw3x3 + attention with COLUMN-MAJOR q/k planes.
//   q,k planes arrive [ch][j=w][i=h]  -> dw is a row-wise vectorized conv
//   with transposed taps, written straight into the swizzled Qt/Kt MFMA
//   operand buffers. No transpose gather. L2-norm ssq = in-wave shfl reduce.
//   v plane arrives row-major [ch][i][j] (unchanged path).
//   Phase staging uses async split: next-phase global loads issued into
//   registers before the conv, written to LDS after the barrier.
// ---------------------------------------------------------------------------
__global__ __launch_bounds__(512, 4) void k_attn(const u16* __restrict__ qkv,
                                                 const float* __restrict__ dww,
                                                 const float* __restrict__ dwb,
                                                 const float* __restrict__ temp,
                                                 u16* __restrict__ outp) {
    extern __shared__ char smem[];
    u16* Qt = (u16*)smem;                  // [j][i] swizzled, 32 KB; Pt aliases
    u16* Kt = Qt + 16384;                  // [k][i] swizzled, 32 KB; Osh aliases
    u16* Vr = (u16*)smem;                  // [128][144] raw V (aliases Qt/Kt)
    u16* Sg = Qt + 32768;                  // [34][144] staging = 9792 B
    float* rqk = (float*)(smem + 75328);   // [2][128] inv-norms (1 KB)
    u16* Pt = Qt;
    u16* Osh = Kt;

    const int ch = blockIdx.x, b = blockIdx.y;
    const int head = ch >> 5;
    const int t = threadIdx.x;
    const size_t qoff = ((size_t)(b * 384 + ch)) << 14;
    const size_t koff = qoff + ((size_t)128 << 14);
    const size_t voff = qoff + ((size_t)256 << 14);

    const int wave = t >> 6, lane = t & 63, m16 = lane & 15, quad = lane >> 4;

    // ---- phase V: stage raw V plane (row-major), dw'd vfr in registers ----
#pragma unroll
    for (int i = 0; i < 4; ++i) {
        int idx = i * 512 + t;
        int r = idx >> 4, c16 = idx & 15;
        *(uint4*)(&Vr[r * 144 + 8 + c16 * 8]) =
            *(const uint4*)(&qkv[voff + ((size_t)r << 7) + c16 * 8]);
    }
    if (t < 256) {
        int r = t >> 1, side = t & 1;
        uint4 z = {0, 0, 0, 0};
        *(uint4*)(&Vr[r * 144 + side * 136]) = z;
    }
    __syncthreads();

    bf16x8 vfr[4];
    {
        float wv9[9];
        const float* wp = dww + (size_t)(256 + ch) * 9;
#pragma unroll
        for (int i = 0; i < 9; ++i) wv9[i] = wp[i];
        const float bvv = dwb[256 + ch];
        const int r = wave * 16 + m16;
#pragma unroll
        for (int kk = 0; kk < 4; ++kk) {
            const int c0 = quad * 8 + kk * 32;
            float acc[8];
#pragma unroll
            for (int c = 0; c < 8; ++c) acc[c] = bvv;
#pragma unroll
            for (int dy = 0; dy < 3; ++dy) {
                int rr = r + dy - 1;
                if ((unsigned)rr < 128u) {
                    const u16* row = &Vr[rr * 144 + 8 + c0];
                    float v0 = bf2f(row[-1]);
                    uint4 m = *(const uint4*)row;
                    float v1 = bf2f((u16)(m.x & 0xffff)), v2 = bf2f((u16)(m.x >> 16));
                    float v3 = bf2f((u16)(m.y & 0xffff)), v4 = bf2f((u16)(m.y >> 16));
                    float v5 = bf2f((u16)(m.z & 0xffff)), v6 = bf2f((u16)(m.z >> 16));
                    float v7 = bf2f((u16)(m.w & 0xffff)), v8 = bf2f((u16)(m.w >> 16));
                    float v9 = bf2f(row[8]);
                    const float w0 = wv9[dy * 3], w1 = wv9[dy * 3 + 1], w2 = wv9[dy * 3 + 2];
                    acc[0] += w0 * v0 + w1 * v1 + w2 * v2;
                    acc[1] += w0 * v1 + w1 * v2 + w2 * v3;
                    acc[2] += w0 * v2 + w1 * v3 + w2 * v4;
                    acc[3] += w0 * v3 + w1 * v4 + w2 * v5;
                    acc[4] += w0 * v4 + w1 * v5 + w2 * v6;
                    acc[5] += w0 * v5 + w1 * v6 + w2 * v7;
                    acc[6] += w0 * v6 + w1 * v7 + w2 * v8;
                    acc[7] += w0 * v7 + w1 * v8 + w2 * v9;
                }
            }
            bf16x8 a;
#pragma unroll
            for (int c = 0; c < 8; ++c) a[c] = (short)f2bf(acc[c]);
            vfr[kk] = a;
        }
    }
    __syncthreads();   // Vr dead; Qt/Kt region now reusable

    // ---- Q/K: 8 phases (4 per matrix), 32 physical rows (j) per phase. ----
    // Sg halo cols (i=-1 at col 7, i=128 at col 136) zeroed once:
    if (t < 68) {
        int r = t >> 1, side = t & 1;
        uint4 z = {0, 0, 0, 0};
        *(uint4*)(&Sg[r * 144 + side * 136]) = z;
    }

    const int sr = t >> 4, sc16 = t & 15;          // staging slot (544 slots)
    const int jloc = t >> 4, seg = t & 15;         // conv thread (512 slots)

    // prologue: stage phase 0 (q rows -1..32)
    {
        int grow = sr - 1;
        uint4 v = {0, 0, 0, 0};
        if ((unsigned)grow < 128u)
            v = *(const uint4*)(&qkv[qoff + ((size_t)grow << 7) + sc16 * 8]);
        *(uint4*)(&Sg[sr * 144 + 8 + sc16 * 8]) = v;
        if (t < 32) {
            int r2 = 32 + (t >> 4);
            int g2 = r2 - 1;
            uint4 v2 = {0, 0, 0, 0};
            if ((unsigned)g2 < 128u)
                v2 = *(const uint4*)(&qkv[qoff + ((size_t)g2 << 7) + sc16 * 8]);
            *(uint4*)(&Sg[r2 * 144 + 8 + sc16 * 8]) = v2;
        }
    }
    __syncthreads();

#pragma unroll 1
    for (int ph = 0; ph < 8; ++ph) {
        const int mat = ph >> 2;
        const int j0 = (ph & 3) * 32;
        const size_t moff = mat ? koff : qoff;

        // async prefetch of next phase into registers
        uint4 pf0 = {0, 0, 0, 0}, pf1 = {0, 0, 0, 0};
        if (ph < 7) {
            const int matn = (ph + 1) >> 2;
            const int j0n = ((ph + 1) & 3) * 32;
            const size_t moffn = matn ? koff : qoff;
            int grow = j0n - 1 + sr;
            if ((unsigned)grow < 128u)
                pf0 = *(const uint4*)(&qkv[moffn + ((size_t)grow << 7) + sc16 * 8]);
            if (t < 32) {
                int g2 = j0n - 1 + 32 + (t >> 4);
                if ((unsigned)g2 < 128u)
                    pf1 = *(const uint4*)(&qkv[moffn + ((size_t)g2 << 7) + sc16 * 8]);
            }
        }
        (void)moff;

        // dw conv with TRANSPOSED taps (plane is column-major):
        //   out[j][i] = sum_{pr,pc} w9[pc*3+pr] * P[j+pr-1][i+pc-1]
        float wg9[9];
        {
            const float* wp = dww + (size_t)(mat * 128 + ch) * 9;
#pragma unroll
            for (int i = 0; i < 9; ++i) wg9[i] = wp[i];
        }
        const float gb = dwb[mat * 128 + ch];

        float acc[8];
#pragma unroll
        for (int c = 0; c < 8; ++c) acc[c] = gb;
#pragma unroll
        for (int pr = 0; pr < 3; ++pr) {
            const u16* row = &Sg[(jloc + pr) * 144 + 8 + seg * 8];
            float v0 = bf2f(row[-1]);
            uint4 m = *(const uint4*)row;
            float v1 = bf2f((u16)(m.x & 0xffff)), v2 = bf2f((u16)(m.x >> 16));
            float v3 = bf2f((u16)(m.y & 0xffff)), v4 = bf2f((u16)(m.y >> 16));
            float v5 = bf2f((u16)(m.z & 0xffff)), v6 = bf2f((u16)(m.z >> 16));
            float v7 = bf2f((u16)(m.w & 0xffff)), v8 = bf2f((u16)(m.w >> 16));
            float v9 = bf2f(row[8]);
            const float w0 = wg9[pr], w1 = wg9[3 + pr], w2 = wg9[6 + pr];
            acc[0] += w0 * v0 + w1 * v1 + w2 * v2;
            acc[1] += w0 * v1 + w1 * v2 + w2 * v3;
            acc[2] += w0 * v2 + w1 * v3 + w2 * v4;
            acc[3] += w0 * v3 + w1 * v4 + w2 * v5;
            acc[4] += w0 * v4 + w1 * v5 + w2 * v6;
            acc[5] += w0 * v5 + w1 * v6 + w2 * v7;
            acc[6] += w0 * v6 + w1 * v7 + w2 * v8;
            acc[7] += w0 * v7 + w1 * v8 + w2 * v9;
        }
        u16 tmp[8];
        float ssq = 0.f;
#pragma unroll
        for (int c = 0; c < 8; ++c) {
            u16 uv = f2bf(acc[c]);
            tmp[c] = uv;
            float f = bf2f(uv);
            ssq += f * f;
        }
        ssq += __shfl_xor(ssq, 1);
        ssq += __shfl_xor(ssq, 2);
        ssq += __shfl_xor(ssq, 4);
        ssq += __shfl_xor(ssq, 8);
        const int j = j0 + jloc;
        if (seg == 0) rqk[mat * 128 + j] = ssq;
        u16* dst = (mat ? Kt : Qt) + j * 128 + ((seg ^ (j & 15)) << 3);
        *(uint4*)dst = *(const uint4*)tmp;

        __syncthreads();   // all Sg reads done
        if (ph < 7) {
            *(uint4*)(&Sg[sr * 144 + 8 + sc16 * 8]) = pf0;
            if (t < 32) *(uint4*)(&Sg[(32 + (t >> 4)) * 144 + 8 + sc16 * 8]) = pf1;
        }
        __syncthreads();   // Sg ready for next phase
    }

    if (t < 256) rqk[t] = 1.0f / fmaxf(sqrtf(rqk[t]), 1e-12f);
    __syncthreads();

    f32x4 S[8] = {};
#pragma unroll
    for (int kk = 0; kk < 4; ++kk) {
        const int sw = ((kk * 4 + quad) ^ m16) << 3;
        bf16x8 bf = *(const bf16x8*)(&Kt[(wave * 16 + m16) * 128 + sw]);
#pragma unroll
        for (int jt = 0; jt < 8; ++jt) {
            bf16x8 af = *(const bf16x8*)(&Qt[(jt * 16 + m16) * 128 + sw]);
            S[jt] = MFMA16(af, bf, S[jt]);
        }
    }

    const float sc = temp[head] * rqk[128 + wave * 16 + m16];
    float vals[8][4];
    float vmax = -1e30f;
#pragma unroll
    for (int jt = 0; jt < 8; ++jt)
#pragma unroll
        for (int r = 0; r < 4; ++r) {
            float v = S[jt][r] * (rqk[jt * 16 + quad * 4 + r] * sc);
            vals[jt][r] = v;
            vmax = fmaxf(vmax, v);
        }
    vmax = fmaxf(vmax, __shfl_xor(vmax, 16));
    vmax = fmaxf(vmax, __shfl_xor(vmax, 32));
    float sum = 0.f;
#pragma unroll
    for (int jt = 0; jt < 8; ++jt)
#pragma unroll
        for (int r = 0; r < 4; ++r) {
            float e = __expf(vals[jt][r] - vmax);
            vals[jt][r] = e;
            sum += e;
        }
    sum += __shfl_xor(sum, 16);
    sum += __shfl_xor(sum, 32);
    const float inv = 1.0f / sum;

    __syncthreads();

    {
        const int k = wave * 16 + m16;
        u16* prow = Pt + k * 128;
#pragma unroll
        for (int jt = 0; jt < 8; ++jt)
#pragma unroll
            for (int pr = 0; pr < 2; ++pr) {
                int j0w = jt * 16 + quad * 4 + pr * 2;
                u32 pk = (u32)f2bf(vals[jt][pr * 2] * inv) |
                         ((u32)f2bf(vals[jt][pr * 2 + 1] * inv) << 16);
                *(u32*)(prow + (((j0w >> 3) ^ (k & 15)) << 3) + (j0w & 7)) = pk;
            }
    }
    __syncthreads();

    f32x4 O[8] = {};
#pragma unroll
    for (int kk = 0; kk < 4; ++kk) {
        const int sw = ((kk * 4 + quad) ^ m16) << 3;
#pragma unroll
        for (int nt = 0; nt < 8; ++nt) {
            bf16x8 bf = *(const bf16x8*)(&Pt[(nt * 16 + m16) * 128 + sw]);
            O[nt] = MFMA16(vfr[kk], bf, O[nt]);
        }
    }

#pragma unroll
    for (int nt = 0; nt < 8; ++nt) {
        int k = nt * 16 + m16;
#pragma unroll
        for (int r = 0; r < 4; ++r) {
            int i = wave * 16 + quad * 4 + r;
            Osh[i * 128 + (((k >> 3) ^ (i & 15)) << 3) + (k & 7)] = f2bf(O[nt][r]);
        }
    }
    __syncthreads();

    u16* ob = outp + (((size_t)(b * 128 + ch)) << 14);
#pragma unroll
    for (int it = 0; it < 4; ++it) {
        int idx = it * 512 + t;
        int row = idx >> 4, gk = idx & 15;
        uint4 v = *(const uint4*)(&Osh[row * 128 + ((gk ^ (row & 15)) << 3)]);
        *(uint4*)(&ob[(row << 7) + gk * 8]) = v;
    }
}

// ---------------------------------------------------------------------------
// K4 v2: proj 1x1 conv.  Staged-panel gather transpose + direct fp32 stores.
// ---------------------------------------------------------------------------
__global__ __launch_bounds__(512, 6) void k_proj(const u16* __restrict__ ain,
                                                 const float* __restrict__ w,
                                                 const float* __restrict__ bias,
                                                 float* __restrict__ outp) {
    extern __shared__ char smem[];
    u16* Bt = (u16*)smem;            // 32 KB swizzled [p][g]
    u16* Sg = Bt + 16384;            // [32][144] staging (9 KB)
    const int h = blockIdx.x, b = blockIdx.y;
    const int t = threadIdx.x;

    const int ldr = t >> 4, ldj8 = t & 15;
    const int gig = t >> 7, gp = t & 127;
    const u16* gcol = &Sg[(gig * 8) * 144 + gp];
    u16* gdst = Bt + gp * 128;
#pragma unroll
    for (int ph = 0; ph < 4; ++ph) {
        int ch = ph * 32 + ldr;
        *(uint4*)(&Sg[ldr * 144 + ldj8 * 8]) =
            *(const uint4*)(&ain[(((size_t)(b * 128 + ch)) << 14) + (h << 7) + ldj8 * 8]);
        __syncthreads();
        u16 tmp[8];
#pragma unroll
        for (int c = 0; c < 8; ++c) tmp[c] = gcol[c * 144];
        int g = ph * 4 + gig;
        *(uint4*)(gdst + ((g ^ (gp & 15)) << 3)) = *(const uint4*)tmp;
        __syncthreads();
    }

    const int wave = t >> 6, lane = t & 63, m16 = lane & 15, quad = lane >> 4;
    bf16x8 afr[4];
    {
        const float* wp0 = w + (size_t)(wave * 16 + m16) * 128 + quad * 8;
#pragma unroll
        for (int kk = 0; kk < 4; ++kk) {
            float4 w0 = *(const float4*)(wp0 + kk * 32);
            float4 w1 = *(const float4*)(wp0 + kk * 32 + 4);
            bf16x8 a;
            a[0] = (short)f2bf(w0.x); a[1] = (short)f2bf(w0.y);
            a[2] = (short)f2bf(w0.z); a[3] = (short)f2bf(w0.w);
            a[4] = (short)f2bf(w1.x); a[5] = (short)f2bf(w1.y);
            a[6] = (short)f2bf(w1.z); a[7] = (short)f2bf(w1.w);
            afr[kk] = a;
        }
    }

    f32x4 acc[8] = {};
#pragma unroll
    for (int kk = 0; kk < 4; ++kk) {
        const int g = kk * 4 + quad;
#pragma unroll
        for (int nt = 0; nt < 8; ++nt) {
            int p = nt * 16 + m16;
            bf16x8 bf = *(const bf16x8*)(&Bt[p * 128 + ((g ^ (p & 15)) << 3)]);
            acc[nt] = MFMA16(afr[kk], bf, acc[nt]);
        }
    }

    float bv[4];
#pragma unroll
    for (int r = 0; r < 4; ++r) bv[r] = bias[wave * 16 + quad * 4 + r];
    float* ob = outp + (((size_t)(b * 128)) << 14) + (h << 7);
#pragma unroll
    for (int nt = 0; nt < 8; ++nt) {
        int p = nt * 16 + m16;
#pragma unroll
        for (int r = 0; r < 4; ++r) {
            int co = wave * 16 + quad * 4 + r;
            ob[((size_t)co << 14) + p] = acc[nt][r] + bv[r];
        }
    }
}

// ---------------------------------------------------------------------------
extern "C" void kernel_launch(void* const* d_in, const int* in_sizes, int n_in,
                              void* d_out, int out_size, void* d_ws, size_t ws_size,
                              hipStream_t stream) {
    const float* x      = (const float*)d_in[0];
    const float* qkv_w  = (const float*)d_in[1];
    const float* qkv_b  = (const float*)d_in[2];
    const float* dw_w   = (const float*)d_in[3];
    const float* dw_b   = (const float*)d_in[4];
    const float* proj_w = (const float*)d_in[5];
    const float* proj_b = (const float*)d_in[6];
    const float* temp   = (const float*)d_in[7];
    float* out = (float*)d_out;

    u16* buf1 = (u16*)d_ws;
    u16* buf2 = buf1 + (size_t)8 * 384 * 16384;

    hipFuncSetAttribute((const void*)k_qkv_t<true>,  hipFuncAttributeMaxDynamicSharedMemorySize, 50176);
    hipFuncSetAttribute((const void*)k_qkv_t<false>, hipFuncAttributeMaxDynamicSharedMemorySize, 50176);
    hipFuncSetAttribute((const void*)k_attn, hipFuncAttributeMaxDynamicSharedMemorySize, 76352);
    hipFuncSetAttribute((const void*)k_proj, hipFuncAttributeMaxDynamicSharedMemorySize, 41984);

    k_xpose<<<dim3(128, 8), 256, 0, stream>>>(x, buf2);
    // q,k planes column-major; v plane row-major
    k_qkv_t<true><<<dim3(128, 2, 8), 512, 50176, stream>>>(buf2, qkv_w, qkv_b, buf1, 0);
    k_qkv_t<false><<<dim3(128, 1, 8), 512, 50176, stream>>>(buf2, qkv_w, qkv_b, buf1, 2);
    k_attn<<<dim3(128, 8), 512, 76352, stream>>>(buf1, dw_w, dw_b, temp, buf2);
    k_proj<<<dim3(128, 8), 512, 41984, stream>>>(buf2, proj_w, proj_b, out);
}